// Round 1
// baseline (3508.712 us; speedup 1.0000x reference)
//
#include <hip/hip_runtime.h>
#include <hip/hip_fp16.h>
#include <cstdint>

#define BATCH 256
#define SEQ   2048
#define IN_DIM 4
#define HID   256
#define G4    1024   // 4*HID

// ---------- helpers ----------

typedef _Float16 h2_t __attribute__((ext_vector_type(2)));

union U32H2 { uint32_t u; h2_t h; __half2 hh; };

__device__ __forceinline__ float fdot2(uint32_t w, uint32_t h, float acc) {
#if __has_builtin(__builtin_amdgcn_fdot2)
    U32H2 a; a.u = w; U32H2 b; b.u = h;
    return __builtin_amdgcn_fdot2(a.h, b.h, acc, false);
#else
    U32H2 a; a.u = w; U32H2 b; b.u = h;
    float2 fa = __half22float2(a.hh), fb = __half22float2(b.hh);
    return acc + fa.x * fb.x + fa.y * fb.y;
#endif
}

__device__ __forceinline__ uint32_t pack_h2(float a, float b) {
    U32H2 u; u.hh = __floats2half2_rn(a, b); return u.u;
}

__device__ __forceinline__ float sigmoidf_(float x) {
    return 1.0f / (1.0f + __expf(-x));
}
__device__ __forceinline__ float tanhf_(float x) {
    return 1.0f - 2.0f / (__expf(2.0f * x) + 1.0f);
}

// ---------- ws layout (bytes) ----------
#define OFF_WTAIL 393216
#define OFF_BIAS  524288
#define OFF_CONVF 528384
#define OFF_KSIM  529408
#define OFF_HOUT  530432

// ---------- prep: fp16 conversion + bias fuse ----------
// New layout for the K-split recurrence:
//   per row (1024 rows), 128 pair-cols split into two K-halves of 64:
//     half0 = pair-cols [0,64):   regs = [0,48),   tail = [48,64)
//     half1 = pair-cols [64,128): regs = [64,112), tail = [112,128)
//   wreg  logical [96][1024]: kk<48 -> pc=kk (half0), kk>=48 -> pc=kk+16 (half1)
//   wtail [8 planes][1024 rows] uint4: plane = half*4 + chunk, chunk pc base
//     half0 plane c covers pc 48+4c..48+4c+3 ; half1 plane c covers 112+4c..
__global__ void prep_kernel(const float* __restrict__ Whh,
                            const float* __restrict__ bih,
                            const float* __restrict__ bhh,
                            uint32_t* __restrict__ wreg,
                            uint32_t* __restrict__ wtail,
                            float* __restrict__ bias) {
    int gid = blockIdx.x * blockDim.x + threadIdx.x;  // 0..131071
    int row = gid >> 7;      // 0..1023
    int pr  = gid & 127;     // pair-col 0..127
    float a = Whh[row * HID + 2 * pr];
    float b = Whh[row * HID + 2 * pr + 1];
    uint32_t p = pack_h2(a, b);
    if (pr < 48) {
        wreg[pr * G4 + row] = p;                       // half0 regs, kk = pr
    } else if (pr < 64) {
        int q = pr - 48; int c = q >> 2, d = q & 3;    // half0 tail
        wtail[((0 * 4 + c) * G4 + row) * 4 + d] = p;
    } else if (pr < 112) {
        wreg[(pr - 16) * G4 + row] = p;                // half1 regs, kk = pr-16
    } else {
        int q = pr - 112; int c = q >> 2, d = q & 3;   // half1 tail
        wtail[((4 + c) * G4 + row) * 4 + d] = p;
    }
    if (gid < G4) bias[gid] = bih[gid] + bhh[gid];
}

// ---------- features: conv mean + RBF kernel sim ----------
__global__ void feat_kernel(const float* __restrict__ x,
                            const float* __restrict__ conv_w,
                            const float* __restrict__ conv_b,
                            float* __restrict__ convf,
                            float* __restrict__ ksim) {
    int b = blockIdx.x, t = threadIdx.x;  // 256 threads
    const float4* xb = (const float4*)(x + (size_t)b * SEQ * IN_DIM);
    float cw0 = conv_w[0], cw1 = conv_w[1], cw2 = conv_w[2], cw3 = conv_w[3];
    float cb = conv_b[0];
    float s_sig = 0.f, s_sq = 0.f;
#pragma unroll
    for (int k = 0; k < 8; ++k) {
        int s = t + k * 256;
        float4 v = xb[s];
        float d = v.x * cw0 + v.y * cw1 + v.z * cw2 + v.w * cw3 + cb;
        s_sig += sigmoidf_(d);
        s_sq  += v.x * v.x + v.y * v.y + v.z * v.z + v.w * v.w;
    }
    __shared__ float sA[256], sB[256];
    sA[t] = s_sig; sB[t] = s_sq;
    __syncthreads();
    for (int off = 128; off > 0; off >>= 1) {
        if (t < off) { sA[t] += sA[t + off]; sB[t] += sB[t + off]; }
        __syncthreads();
    }
    if (t == 0) {
        convf[b] = sA[0] * (1.0f / 2048.0f);
        ksim[b]  = __expf(-sB[0]);
    }
}

// ---------- LSTM recurrence: 1 sample per block ----------
// 512 threads = 8 waves. Thread = (unit u, K-half):
//   u    = wave*32 + (lane&31)  in [0,256)
//   half = lane>>5              which half of the 256-dim h it dots against
// Each thread owns ALL FOUR gate rows of unit u (i=u, f=u+256, g=u+512,
// o=u+768) over its K-half: 4 rows x 48 reg pair-cols + 4 rows x 16 LDS tail
// pair-cols. Cross-half reduce via __shfl_xor(32) (same wave). c/h update is
// thread-local -> ONE barrier per step, no p-buffer.
// LDS reads/thread/step: 16 h-broadcast b128 + 16 tail b128 (was 48 total).
#define TAIL_DW (8 * 1024 * 4)

__global__ __launch_bounds__(512, 2)
void recur_kernel(const float* __restrict__ x,
                  const float* __restrict__ Wih,
                  const uint32_t* __restrict__ wreg,
                  const uint32_t* __restrict__ wtail,
                  const float* __restrict__ bias,
                  float* __restrict__ h_out) {
    extern __shared__ uint32_t smem[];
    uint32_t* tail  = smem;                 // 32768 dwords (8192 uint4, 128KB)
    uint32_t* hbuf0 = smem + TAIL_DW;       // 128 dwords (256 fp16)
    uint32_t* hbuf1 = hbuf0 + 128;          // 128 dwords

    const int b = blockIdx.x;
    const int t = threadIdx.x;
    const int lane = t & 63;
    const int half = lane >> 5;                    // K-half 0/1
    const int u = (t >> 6) * 32 + (lane & 31);     // hidden unit 0..255

    // stage w-tail into LDS (coalesced, layout identical to global)
    {
        const uint4* src = (const uint4*)wtail;
        uint4* dst = (uint4*)tail;
#pragma unroll
        for (int i = 0; i < 16; ++i) dst[t + i * 512] = src[t + i * 512];
    }
    if (t < 128) hbuf0[t] = 0u;  // h = 0 (fp16 zeros)

    const int r0 = u, r1 = u + 256, r2 = u + 512, r3 = u + 768;

    // register-resident weights: 48 pair-cols of this K-half for 4 rows
    uint32_t w0[48], w1_[48], w2_[48], w3_[48];
#pragma unroll
    for (int k = 0; k < 48; ++k) {
        const uint32_t* base = wreg + (size_t)(half * 48 + k) * G4;
        w0[k]  = base[r0];
        w1_[k] = base[r1];
        w2_[k] = base[r2];
        w3_[k] = base[r3];
    }
    // opaque no-op: pin values in VGPRs, forbid rematerialized reloads
#pragma unroll
    for (int k = 0; k < 48; ++k) {
        asm volatile("" : "+v"(w0[k]), "+v"(w1_[k]), "+v"(w2_[k]), "+v"(w3_[k]));
    }

    const float4 wv0 = ((const float4*)Wih)[r0];
    const float4 wv1 = ((const float4*)Wih)[r1];
    const float4 wv2 = ((const float4*)Wih)[r2];
    const float4 wv3 = ((const float4*)Wih)[r3];
    const float bs0 = bias[r0], bs1 = bias[r1], bs2 = bias[r2], bs3 = bias[r3];

    float c_state = 0.f;
    float h_last = 0.f;
    const float4* xb = (const float4*)(x + (size_t)b * SEQ * IN_DIM);

    // per-row tail bases: plane (half*4 + c), row r  -> uint4 index
    const uint4* tq0 = (const uint4*)tail + (size_t)half * 4 * G4 + r0;
    const uint4* tq1 = (const uint4*)tail + (size_t)half * 4 * G4 + r1;
    const uint4* tq2 = (const uint4*)tail + (size_t)half * 4 * G4 + r2;
    const uint4* tq3 = (const uint4*)tail + (size_t)half * 4 * G4 + r3;

    __syncthreads();

    uint32_t* hr = hbuf0;
    uint32_t* hw = hbuf1;

    for (int s = 0; s < SEQ; ++s) {
        const float4 xt = xb[s];
        // x-part + bias only on half0; half1 starts at 0 (added after shfl)
        float i0 = bs0 + xt.x * wv0.x + xt.y * wv0.y + xt.z * wv0.z + xt.w * wv0.w;
        float i1 = bs1 + xt.x * wv1.x + xt.y * wv1.y + xt.z * wv1.z + xt.w * wv1.w;
        float i2 = bs2 + xt.x * wv2.x + xt.y * wv2.y + xt.z * wv2.z + xt.w * wv2.w;
        float i3 = bs3 + xt.x * wv3.x + xt.y * wv3.y + xt.z * wv3.z + xt.w * wv3.w;
        float a0 = half ? 0.f : i0;
        float a1 = half ? 0.f : i1;
        float a2 = half ? 0.f : i2;
        float a3 = half ? 0.f : i3;
        float b0 = 0.f, b1 = 0.f, b2 = 0.f, b3 = 0.f;

        // this thread's half of h: chunks [half*16, half*16+16)
        const uint4* hr4 = (const uint4*)hr + (half << 4);

        // main: pair-cols from registers (12 chunks x 4 pairs)
#pragma unroll
        for (int c = 0; c < 12; ++c) {
            const uint4 h4 = hr4[c];
            a0 = fdot2(w0[4 * c + 0], h4.x, a0); b0 = fdot2(w0[4 * c + 1], h4.y, b0);
            a0 = fdot2(w0[4 * c + 2], h4.z, a0); b0 = fdot2(w0[4 * c + 3], h4.w, b0);
            a1 = fdot2(w1_[4 * c + 0], h4.x, a1); b1 = fdot2(w1_[4 * c + 1], h4.y, b1);
            a1 = fdot2(w1_[4 * c + 2], h4.z, a1); b1 = fdot2(w1_[4 * c + 3], h4.w, b1);
            a2 = fdot2(w2_[4 * c + 0], h4.x, a2); b2 = fdot2(w2_[4 * c + 1], h4.y, b2);
            a2 = fdot2(w2_[4 * c + 2], h4.z, a2); b2 = fdot2(w2_[4 * c + 3], h4.w, b2);
            a3 = fdot2(w3_[4 * c + 0], h4.x, a3); b3 = fdot2(w3_[4 * c + 1], h4.y, b3);
            a3 = fdot2(w3_[4 * c + 2], h4.z, a3); b3 = fdot2(w3_[4 * c + 3], h4.w, b3);
        }
        // tail: last 16 pair-cols of this half from LDS (4 chunks)
#pragma unroll
        for (int c = 0; c < 4; ++c) {
            const uint4 h4 = hr4[12 + c];
            const uint4 t0 = tq0[c * G4];
            const uint4 t1 = tq1[c * G4];
            const uint4 t2 = tq2[c * G4];
            const uint4 t3 = tq3[c * G4];
            a0 = fdot2(t0.x, h4.x, a0); b0 = fdot2(t0.y, h4.y, b0);
            a0 = fdot2(t0.z, h4.z, a0); b0 = fdot2(t0.w, h4.w, b0);
            a1 = fdot2(t1.x, h4.x, a1); b1 = fdot2(t1.y, h4.y, b1);
            a1 = fdot2(t1.z, h4.z, a1); b1 = fdot2(t1.w, h4.w, b1);
            a2 = fdot2(t2.x, h4.x, a2); b2 = fdot2(t2.y, h4.y, b2);
            a2 = fdot2(t2.z, h4.z, a2); b2 = fdot2(t2.w, h4.w, b2);
            a3 = fdot2(t3.x, h4.x, a3); b3 = fdot2(t3.y, h4.y, b3);
            a3 = fdot2(t3.z, h4.z, a3); b3 = fdot2(t3.w, h4.w, b3);
        }

        float z0 = a0 + b0, z1 = a1 + b1, z2 = a2 + b2, z3 = a3 + b3;
        // cross-half reduce (partner = lane^32, same wave)
        z0 += __shfl_xor(z0, 32);
        z1 += __shfl_xor(z1, 32);
        z2 += __shfl_xor(z2, 32);
        z3 += __shfl_xor(z3, 32);

        const float ig = sigmoidf_(z0);
        const float fg = sigmoidf_(z1);
        const float gg = tanhf_(z2);
        const float og = sigmoidf_(z3);
        c_state = fg * c_state + ig * gg;
        h_last  = og * tanhf_(c_state);

        if (half == 0) ((__half*)hw)[u] = __float2half_rn(h_last);
        __syncthreads();
        uint32_t* tmp = hr; hr = hw; hw = tmp;
    }

    if (half == 0) h_out[b * HID + u] = h_last;
}

// ---------- head: fc + relu + out + softmax ----------
__global__ void head_kernel(const float* __restrict__ fc_w,
                            const float* __restrict__ fc_b,
                            const float* __restrict__ out_w,
                            const float* __restrict__ out_b,
                            const float* __restrict__ convf,
                            const float* __restrict__ ksim,
                            const float* __restrict__ h_out,
                            float* __restrict__ out) {
    int b = blockIdx.x, j = threadIdx.x;  // 256 threads
    const float* hrow = h_out + b * HID;
    const float* w = fc_w + j * (HID + 2);
    float acc = fc_b[j] + w[0] * convf[b] + w[HID + 1] * ksim[b];
#pragma unroll 8
    for (int k = 0; k < HID; ++k) acc += w[1 + k] * hrow[k];
    float hid = fmaxf(acc, 0.f);
    __shared__ float r0[256], r1[256];
    r0[j] = hid * out_w[j];
    r1[j] = hid * out_w[HID + j];
    __syncthreads();
    for (int off = 128; off > 0; off >>= 1) {
        if (j < off) { r0[j] += r0[j + off]; r1[j] += r1[j + off]; }
        __syncthreads();
    }
    if (j == 0) {
        float l0 = r0[0] + out_b[0];
        float l1 = r1[0] + out_b[1];
        float m = fmaxf(l0, l1);
        float e0 = __expf(l0 - m), e1 = __expf(l1 - m);
        float inv = 1.0f / (e0 + e1);
        out[b * 2 + 0] = e0 * inv;
        out[b * 2 + 1] = e1 * inv;
    }
}

// ---------- launch ----------
extern "C" void kernel_launch(void* const* d_in, const int* in_sizes, int n_in,
                              void* d_out, int out_size, void* d_ws, size_t ws_size,
                              hipStream_t stream) {
    const float* x      = (const float*)d_in[0];
    const float* conv_w = (const float*)d_in[1];
    const float* conv_b = (const float*)d_in[2];
    const float* Wih    = (const float*)d_in[3];
    const float* Whh    = (const float*)d_in[4];
    const float* bih    = (const float*)d_in[5];
    const float* bhh    = (const float*)d_in[6];
    const float* fcw    = (const float*)d_in[7];
    const float* fcb    = (const float*)d_in[8];
    const float* outw   = (const float*)d_in[9];
    const float* outb   = (const float*)d_in[10];
    float* out = (float*)d_out;

    uint8_t* ws = (uint8_t*)d_ws;
    uint32_t* wreg  = (uint32_t*)ws;
    uint32_t* wtail = (uint32_t*)(ws + OFF_WTAIL);
    float* bias  = (float*)(ws + OFF_BIAS);
    float* convf = (float*)(ws + OFF_CONVF);
    float* ksim  = (float*)(ws + OFF_KSIM);
    float* h_out = (float*)(ws + OFF_HOUT);

    prep_kernel<<<512, 256, 0, stream>>>(Whh, bih, bhh, wreg, wtail, bias);
    feat_kernel<<<BATCH, 256, 0, stream>>>(x, conv_w, conv_b, convf, ksim);

    const size_t smem_bytes = (size_t)(TAIL_DW + 128 + 128) * 4;  // 132096 B
    hipFuncSetAttribute((const void*)recur_kernel,
                        hipFuncAttributeMaxDynamicSharedMemorySize, (int)smem_bytes);
    recur_kernel<<<BATCH, 512, smem_bytes, stream>>>(x, Wih, wreg, wtail, bias, h_out);

    head_kernel<<<BATCH, 256, 0, stream>>>(fcw, fcb, outw, outb, convf, ksim, h_out, out);
}